// Round 3
// baseline (443.678 us; speedup 1.0000x reference)
//
#include <hip/hip_runtime.h>

#define GLOBAL_AS __attribute__((address_space(1)))
#define LDS_AS    __attribute__((address_space(3)))

typedef __bf16 bf16x8 __attribute__((ext_vector_type(8)));
typedef float  f32x16 __attribute__((ext_vector_type(16)));

// Problem dims (fixed by the reference)
constexpr int SRC_STRIDE = 8192 * 80;         // floats per batch row: 655360
constexpr int TOUT       = 2728;              // output time steps
constexpr long OUT_ELEMS = (long)TOUT * 16 * 1024;  // 44695552
constexpr int SRC_ELEMS  = 32 * SRC_STRIDE;   // 20971520
constexpr int W_ELEMS    = 1024 * 640;        // 655360
constexpr int MBLK       = 341;               // 87296 / 256 (exact)

__device__ __forceinline__ unsigned short f2bf(float f) {
    union { float f; unsigned u; } a; a.f = f;
    unsigned r = a.u + 0x7FFF + ((a.u >> 16) & 1);   // round-to-nearest-even
    return (unsigned short)(r >> 16);
}

// fp32 -> bf16 conversion, 4 elements/thread (for A / src)
__global__ void cvt_kernel(const float* __restrict__ in, unsigned short* __restrict__ out, int n4) {
    int i = blockIdx.x * blockDim.x + threadIdx.x;
    if (i >= n4) return;
    float4 v = ((const float4*)in)[i];
    ushort4 o;
    o.x = f2bf(v.x); o.y = f2bf(v.y); o.z = f2bf(v.z); o.w = f2bf(v.w);
    ((ushort4*)out)[i] = o;
}

// W -> bf16, pre-swizzled into MFMA B-fragment order:
// out[((bn*80 + c)*64 + nl)*8 + e] = bf16( W[(bn*64+nl)*640 + c*8 + e] )
// (c = k>>3; so a block's 64-wide N-slice is one contiguous 81920 B region,
//  and global_load_lds staging + ds_read fragments are both perfectly linear)
__global__ void cvt_w_frag(const float* __restrict__ W, unsigned short* __restrict__ out) {
    int i = blockIdx.x * blockDim.x + threadIdx.x;    // 0 .. 81919
    int nl = i & 63;
    int c  = (i >> 6) % 80;
    int bn = i / 5120;
    const float* src = W + (bn * 64 + nl) * 640 + c * 8;
    float4 v0 = ((const float4*)src)[0];
    float4 v1 = ((const float4*)src)[1];
    ushort4 o0, o1;
    o0.x = f2bf(v0.x); o0.y = f2bf(v0.y); o0.z = f2bf(v0.z); o0.w = f2bf(v0.w);
    o1.x = f2bf(v1.x); o1.y = f2bf(v1.y); o1.z = f2bf(v1.z); o1.w = f2bf(v1.w);
    ((ushort4*)(out + (long)i * 8))[0] = o0;
    ((ushort4*)(out + (long)i * 8))[1] = o1;
}

// out_lengths = src_lengths // 3 - 2, written as fp32 after the main output
__global__ void lengths_kernel(const int* __restrict__ len, float* __restrict__ out) {
    int i = threadIdx.x;
    if (i < 32) out[OUT_ELEMS + i] = (float)(len[i] / 3 - 2);
}

// Fused GEMM (M=87296, N=1024, K=640) + bias + GLU, barrier-free K-loop.
// Block: 256 M x 64 N, 512 threads (8 waves), wave w owns t = bm*8+w (32 M rows).
// B slice (64 N x 640 K, frag-ordered) staged ONCE into 80 KB LDS -> 1 barrier.
// A fragments stream from global (L2-hot) into VGPRs, 1-deep prefetch.
// MFMA 32x32x16: C/D row = (reg&3)+8*(reg>>2)+4*(lane>>5), col = lane&31;
// GLU pairs value reg r with gate reg r+8 in the SAME accumulator.
__global__ __launch_bounds__(512, 4) void glu_gemm(
        const __bf16* __restrict__ A,
        const __bf16* __restrict__ Wfrag,
        const float* __restrict__ bias,
        float* __restrict__ out) {
    __shared__ __bf16 lB[40960];   // exactly 81920 B -> 2 blocks/CU

    const int tid  = threadIdx.x;
    const int lane = tid & 63;
    const int w    = tid >> 6;        // wave 0..7
    const int b    = lane & 31;       // batch row within t (= MFMA A row)
    const int q    = lane >> 5;       // k-half within fragment

    // XCD swizzle: all 16 bn-siblings of one bm share bid%8 -> same XCD L2.
    const int bid = blockIdx.x;
    const int bn  = (bid >> 3) & 15;
    const int bm  = (bid >> 7) * 8 + (bid & 7);
    if (bm >= MBLK) return;           // whole-block early out (tail)

    // ---- stage B slice: 81920 B, 10 linear issues of 512 lanes x 16 B ----
    const __bf16* wsrc = Wfrag + (long)bn * 40960;
#pragma unroll
    for (int i = 0; i < 10; ++i) {
        __builtin_amdgcn_global_load_lds(
            (const GLOBAL_AS void*)(wsrc + i * 4096 + tid * 8),
            (LDS_AS void*)(lB + i * 4096 + tid * 8), 16, 0, 0);
    }

    // ---- A per-lane base: m = (bm*8+w)*32 + b  ->  addr is 16B-aligned ----
    const int t_w = bm * 8 + w;
    const __bf16* aptr = A + ((long)b * SRC_STRIDE + t_w * 240 + q * 8);

    // B frag LDS element offsets: kc*2048 + s*1024 + q*512 + nt*256 + b*8
    const int bbase = q * 512 + b * 8;

    // preload kc=0 A frags (drained by the same barrier)
    bf16x8 aC[2], aN[2], bC[2][2], bN[2][2];
    aC[0] = *(const bf16x8*)(aptr);
    aC[1] = *(const bf16x8*)(aptr + 16);

    __syncthreads();                   // the ONLY barrier

    bC[0][0] = *(const bf16x8*)(lB + bbase);
    bC[0][1] = *(const bf16x8*)(lB + bbase + 1024);
    bC[1][0] = *(const bf16x8*)(lB + bbase + 256);
    bC[1][1] = *(const bf16x8*)(lB + bbase + 1024 + 256);

    f32x16 acc[2] = {};

#pragma unroll
    for (int kc = 0; kc < 20; ++kc) {
        if (kc < 19) {
            const int k2 = (kc + 1) * 32;
            aN[0] = *(const bf16x8*)(aptr + k2);
            aN[1] = *(const bf16x8*)(aptr + k2 + 16);
            const int lb = (kc + 1) * 2048 + bbase;
            bN[0][0] = *(const bf16x8*)(lB + lb);
            bN[0][1] = *(const bf16x8*)(lB + lb + 1024);
            bN[1][0] = *(const bf16x8*)(lB + lb + 256);
            bN[1][1] = *(const bf16x8*)(lB + lb + 1024 + 256);
        }
#pragma unroll
        for (int s = 0; s < 2; ++s) {
#pragma unroll
            for (int nt = 0; nt < 2; ++nt)
                acc[nt] = __builtin_amdgcn_mfma_f32_32x32x16_bf16(
                    aC[s], bC[nt][s], acc[nt], 0, 0, 0);
        }
#pragma unroll
        for (int s = 0; s < 2; ++s) { aC[s] = aN[s]; }
#pragma unroll
        for (int nt = 0; nt < 2; ++nt) {
            bC[nt][0] = bN[nt][0]; bC[nt][1] = bN[nt][1];
        }
    }

    // ---- epilogue: bias + GLU, all in-register ----
    const int n0 = bn * 64 + b;
    float bv0 = bias[n0];
    float bv1 = bias[n0 + 32];

#pragma unroll
    for (int nt = 0; nt < 2; ++nt) {
        const float bvv = nt ? bv1 : bv0;
        const long ncol = n0 + nt * 32;
#pragma unroll
        for (int r = 0; r < 8; ++r) {
            const int brow = (r & 3) + 8 * (r >> 2) + 4 * q;  // value row 0..15
            float v = acc[nt][r] + bvv;
            float g = acc[nt][r + 8] + bvv;                    // row brow+16
            float s = 1.0f / (1.0f + __expf(-g));
            out[((long)(t_w * 16 + brow)) * 1024 + ncol] = v * s;
        }
    }
}

extern "C" void kernel_launch(void* const* d_in, const int* in_sizes, int n_in,
                              void* d_out, int out_size, void* d_ws, size_t ws_size,
                              hipStream_t stream) {
    const float* src  = (const float*)d_in[0];
    const int*   lens = (const int*)d_in[1];
    const float* Wf   = (const float*)d_in[2];
    const float* bias = (const float*)d_in[3];
    float* out = (float*)d_out;

    unsigned short* srcb  = (unsigned short*)d_ws;         // 20971520 bf16 = 41.9 MB
    unsigned short* wfrag = srcb + SRC_ELEMS;              // 655360 bf16 = 1.3 MB

    // bf16 pre-passes
    cvt_kernel<<<SRC_ELEMS / 4 / 256, 256, 0, stream>>>(src, srcb, SRC_ELEMS / 4);
    cvt_w_frag<<<W_ELEMS / 8 / 256, 256, 0, stream>>>(Wf, wfrag);

    // out_lengths
    lengths_kernel<<<1, 64, 0, stream>>>(lens, out);

    // fused GEMM + GLU: 43 groups x (16 bn x 8 bm_local) = 5504 blocks (48 idle)
    glu_gemm<<<43 * 128, 512, 0, stream>>>((const __bf16*)srcb,
                                           (const __bf16*)wfrag, bias, out);
}